// Round 3
// baseline (22.648 us; speedup 1.0000x reference)
//
#include <hip/hip_runtime.h>
#include <math.h>

#define HDIM 32
#define NSTEPS 32
#define NSECANT 8
#define RADIUSV 1.0f
#define NEARV 0.5f
#define TAUV 0.5f
#define EPSV 1e-6f

typedef float f2 __attribute__((ext_vector_type(2)));

// exchange with the xor-1 partner lane (BitMode swizzle: xor=1, and=0x1F)
__device__ __forceinline__ float pair_other(float x) {
    return __builtin_bit_cast(float,
        __builtin_amdgcn_ds_swizzle(__builtin_bit_cast(int, x), 0x041F));
}

__global__ __launch_bounds__(256) void unisurf_kernel(
    const float* __restrict__ cam_loc,   // [3]
    const float* __restrict__ ray_dirs,  // [P*3]
    const float* __restrict__ W1,        // [3*HDIM]
    const float* __restrict__ b1,        // [HDIM]
    const float* __restrict__ W2,        // [HDIM]
    const float* __restrict__ b2,        // [1]
    float* __restrict__ out,             // [2*P]: d_pred then occ_surf
    int P)
{
    __shared__ float4 sW[HDIM];   // (w0, w1, w2, b1) per hidden unit
    __shared__ float  sW2[HDIM];
    __shared__ float  sB2;

    const int tid = threadIdx.x;
    if (tid < HDIM) {
        sW[tid] = make_float4(W1[tid], W1[HDIM + tid], W1[2 * HDIM + tid], b1[tid]);
        sW2[tid] = W2[tid];
    }
    if (tid == 0) sB2 = b2[0];
    __syncthreads();

    const int j = blockIdx.x * blockDim.x + tid;
    const int r = j >> 1;          // ray index: 2 threads per ray
    if (r >= P) return;
    const int sub = j & 1;         // 0: units 0..15, 1: units 16..31
    const int ubase = sub * (HDIM / 2);

    // camera (wave-uniform)
    const float cx = cam_loc[0], cy = cam_loc[1], cz = cam_loc[2];

    // ray load + normalize (duplicated in both lanes of the pair)
    float dx = ray_dirs[3 * r + 0];
    float dy = ray_dirs[3 * r + 1];
    float dz = ray_dirs[3 * r + 2];
    float nrm = sqrtf(dx * dx + dy * dy + dz * dz);
    float rx = dx / nrm, ry = dy / nrm, rz = dz / nrm;

    // sphere intersection
    float rcd = rx * cx + ry * cy + rz * cz;
    float c2  = cx * cx + cy * cy + cz * cz;
    float us  = rcd * rcd - (c2 - RADIUSV * RADIUSV);
    bool  mask_int = us > 0.0f;
    float s_sq = mask_int ? sqrtf(us) : 0.0f;
    float far_raw = mask_int ? fmaxf(s_sq - rcd, 0.0f) : 0.0f;
    float farv = fmaxf(far_raw, NEARV + EPSV);

    // this lane's 16 hidden units, factored per-ray:
    //   a_h(d) = cW[h] + d * rW[h];  partial = sum_h relu(a_h)*w2[h]
    f2 rW[8], cW[8], w2[8];
    #pragma unroll
    for (int k = 0; k < 8; ++k) {
        float4 wa = sW[ubase + 2 * k], wb = sW[ubase + 2 * k + 1];
        rW[k] = (f2){rx * wa.x + ry * wa.y + rz * wa.z,
                     rx * wb.x + ry * wb.y + rz * wb.z};
        cW[k] = (f2){cx * wa.x + cy * wa.y + cz * wa.z + wa.w,
                     cx * wb.x + cy * wb.y + cz * wb.z + wb.w};
        w2[k] = (f2){sW2[ubase + 2 * k], sW2[ubase + 2 * k + 1]};
    }
    const float B2 = sB2;
    const f2 z2 = (f2){0.0f, 0.0f};

    // full logit: own half + partner half (pair-uniform call sites only)
    auto logit = [&](float d) -> float {
        f2 dv = (f2){d, d};
        f2 a0 = z2, a1 = z2, a2 = z2, a3 = z2;
        #pragma unroll
        for (int k = 0; k < 8; k += 4) {
            f2 x0 = __builtin_elementwise_fma(dv, rW[k + 0], cW[k + 0]);
            f2 x1 = __builtin_elementwise_fma(dv, rW[k + 1], cW[k + 1]);
            f2 x2 = __builtin_elementwise_fma(dv, rW[k + 2], cW[k + 2]);
            f2 x3 = __builtin_elementwise_fma(dv, rW[k + 3], cW[k + 3]);
            a0 = __builtin_elementwise_fma(__builtin_elementwise_max(x0, z2), w2[k + 0], a0);
            a1 = __builtin_elementwise_fma(__builtin_elementwise_max(x1, z2), w2[k + 1], a1);
            a2 = __builtin_elementwise_fma(__builtin_elementwise_max(x2, z2), w2[k + 2], a2);
            a3 = __builtin_elementwise_fma(__builtin_elementwise_max(x3, z2), w2[k + 3], a3);
        }
        f2 aa = (a0 + a1) + (a2 + a3);
        float p = aa.x + aa.y;
        return p + pair_other(p) + B2;
    };
    auto sigm = [](float x) -> float {   // fast sigmoid: v_exp + v_rcp
        float e = __expf(-x);
        return __builtin_amdgcn_rcpf(1.0f + e);
    };

    // coarse march on logits (sign(sigmoid(x)-0.5) == sign(x))
    float l_prev = logit(NEARV);
    float d_prev = NEARV;
    const float l0 = l_prev;
    float d1v = 0.0f, l1v = 0.0f;

    bool found = false;
    float d_lo = 0.0f, l_lo = 0.0f, d_hi = 0.0f, l_hi = 0.0f;

    const float STEPC = 0.03225806451612903f;  // fl(1/31)
    #pragma unroll 2
    for (int s = 1; s < NSTEPS; ++s) {
        float t = (float)s * STEPC;
        float dd = NEARV * (1.0f - t) + farv * t;
        float ls = logit(dd);
        if (s == 1) { d1v = dd; l1v = ls; }
        if (!found && (l_prev < 0.0f) && (ls >= 0.0f)) {
            found = true;
            d_lo = d_prev; l_lo = l_prev;
            d_hi = dd;     l_hi = ls;
        }
        d_prev = dd; l_prev = ls;
    }
    if (!found) {  // reference: idx = argmax(all-false) = 0
        d_lo = NEARV; l_lo = l0;
        d_hi = d1v;   l_hi = l1v;
    }
    found = found && mask_int;

    // bracket logits -> f = sigmoid - tau for the secant
    float f_lo = sigm(l_lo) - TAUV;
    float f_hi = sigm(l_hi) - TAUV;

    // secant refinement (pair-uniform, duplicated)
    #pragma unroll 1
    for (int it = 0; it < NSECANT; ++it) {
        float den = f_hi - f_lo;
        den = (fabsf(den) < EPSV) ? EPSV : den;
        float dm = d_lo - f_lo * (d_hi - d_lo) * __builtin_amdgcn_rcpf(den);
        float fm = sigm(logit(dm)) - TAUV;
        bool neg = fm < 0.0f;
        d_lo = neg ? dm : d_lo;
        f_lo = neg ? fm : f_lo;
        d_hi = neg ? d_hi : dm;
        f_hi = neg ? f_hi : fm;
    }
    float den = f_hi - f_lo;
    den = (fabsf(den) < EPSV) ? EPSV : den;
    float d_mid = d_lo - f_lo * (d_hi - d_lo) * __builtin_amdgcn_rcpf(den);

    float d_pred = found ? d_mid : 0.0f;
    float occ_s = sigm(logit(d_pred));
    float occ_surf = found ? occ_s : 0.0f;

    if (sub == 0) out[r] = d_pred;
    else          out[P + r] = occ_surf;
}

extern "C" void kernel_launch(void* const* d_in, const int* in_sizes, int n_in,
                              void* d_out, int out_size, void* d_ws, size_t ws_size,
                              hipStream_t stream) {
    const float* cam_loc  = (const float*)d_in[0];
    const float* ray_dirs = (const float*)d_in[1];
    const float* W1       = (const float*)d_in[2];
    const float* b1       = (const float*)d_in[3];
    const float* W2       = (const float*)d_in[4];
    const float* b2       = (const float*)d_in[5];
    float* out = (float*)d_out;

    const int P = in_sizes[1] / 3;
    const int block = 256;
    const long long total = 2LL * P;           // 2 threads per ray
    const int grid = (int)((total + block - 1) / block);
    unisurf_kernel<<<grid, block, 0, stream>>>(cam_loc, ray_dirs, W1, b1, W2, b2, out, P);
}